// Round 8
// baseline (190.648 us; speedup 1.0000x reference)
//
#include <hip/hip_runtime.h>
#include <math.h>

#define N_TOK 13824
#define DM 192
#define DI 384
#define DS 16
#define DTR 12
#define CHUNK 32
#define NCHUNK 432   // 13824 / 32

typedef unsigned short u16;
typedef __attribute__((ext_vector_type(8))) short bf16x8;
typedef __attribute__((ext_vector_type(8))) unsigned short u16x8;
typedef __attribute__((ext_vector_type(4))) float f32x4;

__device__ __forceinline__ float sigmoidf_(float x){ return 1.f/(1.f+__expf(-x)); }
__device__ __forceinline__ u16 f2bf(float f){
  union { float f; unsigned u; } c; c.f = f;
  unsigned u = c.u;
  u += 0x7fffu + ((u>>16)&1u);
  return (u16)(u>>16);
}
__device__ __forceinline__ float bf2f(u16 v){
  union { unsigned u; float f; } c; c.u = ((unsigned)v)<<16; return c.f;
}

// ---------------- Kernel 0: convert W_in / W_out / xpw to bf16 MFMA B-fragment order ----
// Fragment (nt,kt): lane l, elem i  <-  W[kt*32 + (l>>4)*8 + i][nt*16 + (l&15)]
__global__ __launch_bounds__(256) void k0_prep(
    const float* __restrict__ Win, const float* __restrict__ Wout,
    const float* __restrict__ xpw,
    u16* __restrict__ winf, u16* __restrict__ woutf, u16* __restrict__ xpwf)
{
  const int b = blockIdx.x, tid = threadIdx.x;
  if (b < 72) {                       // W_in: 48 nt x 6 kt = 288 frags
    int g = b*256 + tid; int fi = g>>6, lane = g&63;
    int nt = fi/6, kt = fi%6;
    int n = nt*16 + (lane&15);
    int kb = kt*32 + ((lane>>4)<<3);
    u16 v[8];
    #pragma unroll
    for (int i=0;i<8;i++) v[i] = f2bf(Win[(size_t)(kb+i)*768 + n]);
    u16* dst = winf + ((size_t)fi*64 + lane)*8;
    #pragma unroll
    for (int i=0;i<8;i++) dst[i] = v[i];
  } else if (b < 108) {               // W_out: 12 nt x 12 kt = 144 frags
    int g = (b-72)*256 + tid; int fi = g>>6, lane = g&63;
    int nt = fi/12, kt = fi%12;
    int n = nt*16 + (lane&15);
    int kb = kt*32 + ((lane>>4)<<3);
    u16 v[8];
    #pragma unroll
    for (int i=0;i<8;i++) v[i] = f2bf(Wout[(size_t)(kb+i)*192 + n]);
    u16* dst = woutf + ((size_t)fi*64 + lane)*8;
    #pragma unroll
    for (int i=0;i<8;i++) dst[i] = v[i];
  } else {                            // xpw: 3 nt x 12 kt = 36 frags (cols 44..47 zero)
    int g = (b-108)*256 + tid; int fi = g>>6, lane = g&63;
    if (fi < 36) {
      int nt = fi/12, kt = fi%12;
      int n = nt*16 + (lane&15);
      int kb = kt*32 + ((lane>>4)<<3);
      u16 v[8];
      #pragma unroll
      for (int i=0;i<8;i++) v[i] = (n < 44) ? f2bf(xpw[(size_t)(kb+i)*44 + n]) : (u16)0;
      u16* dst = xpwf + ((size_t)fi*64 + lane)*8;
      #pragma unroll
      for (int i=0;i<8;i++) dst[i] = v[i];
    }
  }
}

// ---------------- Kernel 1 (MFMA): LayerNorm(x) @ W_in -> xs (bf16), z (fp32) ----------------
__global__ __launch_bounds__(256) void k1_ln_gemm1(
    const float* __restrict__ x, const float* __restrict__ lnw,
    const float* __restrict__ lnb, const u16* __restrict__ winf,
    u16* __restrict__ xs_bf, float* __restrict__ z)
{
  __shared__ u16 sA[32][200];        // 12.5 KB, stride 400 B -> 2-way bank alias (free)
  const int tid = threadIdx.x;
  const int tok0 = blockIdx.x * 32;
  const int wid = tid>>6, lane = tid&63;

  {
    int t = wid*8 + (lane>>3);
    int l8 = lane&7;
    const float* xrow = x + (size_t)(tok0+t)*192 + l8*4;
    float4 v[6]; float s=0.f, s2=0.f;
    #pragma unroll
    for (int j=0;j<6;j++){
      v[j] = *(const float4*)(xrow + j*32);
      s  += v[j].x+v[j].y+v[j].z+v[j].w;
      s2 += v[j].x*v[j].x + v[j].y*v[j].y + v[j].z*v[j].z + v[j].w*v[j].w;
    }
    #pragma unroll
    for (int off=4; off; off>>=1){ s += __shfl_xor(s, off, 8); s2 += __shfl_xor(s2, off, 8); }
    float m = s*(1.f/192.f);
    float rs = rsqrtf(s2*(1.f/192.f) - m*m + 1e-5f);
    #pragma unroll
    for (int j=0;j<6;j++){
      int k = j*32 + l8*4;
      float4 lw = *(const float4*)(lnw+k);
      float4 lb = *(const float4*)(lnb+k);
      sA[t][k+0] = f2bf((v[j].x-m)*rs*lw.x+lb.x);
      sA[t][k+1] = f2bf((v[j].y-m)*rs*lw.y+lb.y);
      sA[t][k+2] = f2bf((v[j].z-m)*rs*lw.z+lb.z);
      sA[t][k+3] = f2bf((v[j].w-m)*rs*lw.w+lb.w);
    }
  }
  __syncthreads();

  const int wm = wid>>1, wn = wid&1;
  bf16x8 a[6];
  #pragma unroll
  for (int kt=0;kt<6;kt++)
    a[kt] = *(const bf16x8*)&sA[wm*16 + (lane&15)][kt*32 + ((lane>>4)<<3)];

  const bf16x8* wf = (const bf16x8*)winf;
  f32x4 acc[24];
  #pragma unroll
  for (int j=0;j<24;j++) acc[j] = (f32x4){0.f,0.f,0.f,0.f};

  #pragma unroll
  for (int j=0;j<24;j++){
    int nt = wn*24 + j;
    const bf16x8* bp = wf + (size_t)nt*6*64 + lane;
    #pragma unroll
    for (int kt=0;kt<6;kt++)
      acc[j] = __builtin_amdgcn_mfma_f32_16x16x32_bf16(a[kt], bp[kt*64], acc[j], 0,0,0);
  }

  const int r0 = tok0 + wm*16 + ((lane>>4)<<2);
  if (wn == 0){
    #pragma unroll
    for (int j=0;j<24;j++){
      int cc = j*16 + (lane&15);
      #pragma unroll
      for (int r=0;r<4;r++)
        xs_bf[(size_t)(r0+r)*384 + cc] = f2bf(acc[j][r]);
    }
  } else {
    #pragma unroll
    for (int j=0;j<24;j++){
      int cc = j*16 + (lane&15);
      #pragma unroll
      for (int r=0;r<4;r++)
        z[(size_t)(r0+r)*384 + cc] = acc[j][r];
    }
  }
}

// ---------------- Kernel 234 (fused): conv3+SiLU + x_proj MFMA + dt_proj + scan1 ----------------
// One block per chunk (32 tokens), 384 threads. 31 KB LDS -> 4-5 blocks/CU.
// Conv reads xs_bf straight from global (L2-resident); u tile kept bf16 in LDS.
__global__ __launch_bounds__(384) void k234_conv_xproj_scan1(
    const u16* __restrict__ xs_bf, const float* __restrict__ cw, const float* __restrict__ cb,
    const u16* __restrict__ xpwf, const float* __restrict__ dtw, const float* __restrict__ dtb,
    const float* __restrict__ Alog,
    float* __restrict__ u_out, float* __restrict__ delta,
    float* __restrict__ Bc, float* __restrict__ Cc,
    float* __restrict__ P, float* __restrict__ he)
{
  __shared__ u16 sU16[32][392];    // 25.1 KB  bf16 u-tile (K=384 + 8 pad), stride 784 B
  __shared__ float sdbl[32][48];   //  6 KB
  const int tid = threadIdx.x;
  const int c = blockIdx.x; const int n0 = c*CHUNK;

  // conv + silu, thread = channel; reads xs_bf column tid directly from global
  {
    const float w0 = cw[tid*3+0], w1 = cw[tid*3+1], w2 = cw[tid*3+2], bb = cb[tid];
    const u16* xp = xs_bf + tid;
    float vm = (n0 > 0) ? bf2f(xp[(size_t)(n0-1)*384]) : 0.f;
    float vc = bf2f(xp[(size_t)n0*384]);
    #pragma unroll 4
    for (int t=0;t<32;t++){
      int np1 = n0 + t + 1;
      float vp = (np1 < N_TOK) ? bf2f(xp[(size_t)np1*384]) : 0.f;
      float v = fmaf(w0,vm, fmaf(w1,vc, fmaf(w2,vp, bb)));
      float uv = v * sigmoidf_(v);
      u_out[(size_t)(n0+t)*384 + tid] = uv;
      sU16[t][tid] = f2bf(uv);
      vm = vc; vc = vp;
    }
  }
  __syncthreads();

  // x_proj MFMA: 6 waves = 2 M-halves x 3 n-tiles, 12 k-tiles each
  const int wid = tid>>6, lane = tid&63;
  {
    const int wm = wid & 1, wnt = wid >> 1;
    const int arow = wm*16 + (lane&15);
    f32x4 acc = (f32x4){0.f,0.f,0.f,0.f};
    const bf16x8* bp = (const bf16x8*)xpwf + (size_t)wnt*12*64 + lane;
    #pragma unroll
    for (int kt=0;kt<12;kt++){
      bf16x8 a = *(const bf16x8*)&sU16[arow][kt*32 + ((lane>>4)<<3)];
      acc = __builtin_amdgcn_mfma_f32_16x16x32_bf16(a, bp[kt*64], acc, 0,0,0);
    }
    int ccol = wnt*16 + (lane&15);
    int r0 = wm*16 + ((lane>>4)<<2);
    #pragma unroll
    for (int r=0;r<4;r++) sdbl[r0+r][ccol] = acc[r];
  }
  __syncthreads();

  for (int i=tid;i<32*16;i+=384){
    int t=i>>4, s=i&15;
    Bc[(size_t)(n0+t)*16+s] = sdbl[t][12+s];
    Cc[(size_t)(n0+t)*16+s] = sdbl[t][28+s];
  }

  // scan phase 1, thread = channel
  float Ac[16];
  #pragma unroll
  for (int s=0;s<16;s+=4){
    float4 av = *(const float4*)(Alog + tid*16 + s);
    Ac[s]=-__expf(av.x); Ac[s+1]=-__expf(av.y); Ac[s+2]=-__expf(av.z); Ac[s+3]=-__expf(av.w);
  }
  float wr[12];
  #pragma unroll
  for (int r=0;r<12;r++) wr[r] = dtw[r*384 + tid];
  const float db_ = dtb[tid];
  float h[16];
  #pragma unroll
  for (int s=0;s<16;s++) h[s]=0.f;
  float dlsum = 0.f;

  #pragma unroll 4
  for (int t=0;t<32;t++){
    float4 d0 = *(const float4*)&sdbl[t][0];
    float4 d1 = *(const float4*)&sdbl[t][4];
    float4 d2 = *(const float4*)&sdbl[t][8];
    float a0 = db_;
    a0=fmaf(d0.x,wr[0],a0); a0=fmaf(d0.y,wr[1],a0); a0=fmaf(d0.z,wr[2],a0); a0=fmaf(d0.w,wr[3],a0);
    a0=fmaf(d1.x,wr[4],a0); a0=fmaf(d1.y,wr[5],a0); a0=fmaf(d1.z,wr[6],a0); a0=fmaf(d1.w,wr[7],a0);
    a0=fmaf(d2.x,wr[8],a0); a0=fmaf(d2.y,wr[9],a0); a0=fmaf(d2.z,wr[10],a0); a0=fmaf(d2.w,wr[11],a0);
    float dl = fmaxf(a0,0.f) + log1pf(__expf(-fabsf(a0)));
    delta[(size_t)(n0+t)*384 + tid] = dl;
    dlsum += dl;
    float du = dl * bf2f(sU16[t][tid]);
    float4 b0 = *(const float4*)&sdbl[t][12];
    float4 b1 = *(const float4*)&sdbl[t][16];
    float4 b2 = *(const float4*)&sdbl[t][20];
    float4 b3 = *(const float4*)&sdbl[t][24];
    float Bv[16] = {b0.x,b0.y,b0.z,b0.w, b1.x,b1.y,b1.z,b1.w,
                    b2.x,b2.y,b2.z,b2.w, b3.x,b3.y,b3.z,b3.w};
    #pragma unroll
    for (int s=0;s<16;s++){
      float a = __expf(dl * Ac[s]);
      h[s] = fmaf(a, h[s], du * Bv[s]);
    }
  }
  size_t base = (size_t)c*6144 + (size_t)tid*16;
  #pragma unroll
  for (int s=0;s<16;s+=4){
    *(float4*)&P[base+s]  = make_float4(__expf(dlsum*Ac[s]),   __expf(dlsum*Ac[s+1]),
                                        __expf(dlsum*Ac[s+2]), __expf(dlsum*Ac[s+3]));
    *(float4*)&he[base+s] = make_float4(h[s],h[s+1],h[s+2],h[s+3]);
  }
}

// ---------------- Kernel 5: scan phase 2 (cross-chunk prefix, sw-pipelined) ----------------
__global__ __launch_bounds__(256) void k5_scan2(
    const float* __restrict__ P, const float* __restrict__ he, float* __restrict__ hi)
{
  const int idx = blockIdx.x*256 + threadIdx.x;   // 0..6143
  float H = 0.f;
  float pA[8], eA[8], pB[8], eB[8];
  #pragma unroll
  for (int i = 0; i < 8; i++) {
    size_t o = (size_t)i*6144 + idx; pA[i] = P[o]; eA[i] = he[o];
  }
  for (int c0 = 0; c0 < NCHUNK; c0 += 16) {
    #pragma unroll
    for (int i = 0; i < 8; i++) {
      size_t o = (size_t)(c0+8+i)*6144 + idx; pB[i] = P[o]; eB[i] = he[o];
    }
    #pragma unroll
    for (int i = 0; i < 8; i++) {
      size_t o = (size_t)(c0+i)*6144 + idx; hi[o] = H; H = fmaf(pA[i], H, eA[i]);
    }
    if (c0 + 16 < NCHUNK) {
      #pragma unroll
      for (int i = 0; i < 8; i++) {
        size_t o = (size_t)(c0+16+i)*6144 + idx; pA[i] = P[o]; eA[i] = he[o];
      }
    }
    #pragma unroll
    for (int i = 0; i < 8; i++) {
      size_t o = (size_t)(c0+8+i)*6144 + idx; hi[o] = H; H = fmaf(pB[i], H, eB[i]);
    }
  }
}

// ---------------- Kernel 67 (fused): scan phase 3 + LayerNorm(y)*silu(z) -> g_bf ----------------
// sY split into two 16-token halves: 29.3 KB LDS -> 5 blocks/CU.
__global__ __launch_bounds__(384) void k67_scan3_lngate(
    const float* __restrict__ delta, const float* __restrict__ u,
    const float* __restrict__ Bc, const float* __restrict__ Cc,
    const float* __restrict__ Alog, const float* __restrict__ Dp,
    const float* __restrict__ hi, const float* __restrict__ z,
    const float* __restrict__ lnw, const float* __restrict__ lnb,
    u16* __restrict__ g_bf)
{
  __shared__ float sB[CHUNK][16], sC[CHUNK][16];
  __shared__ float sY[16][396];   // 25.3 KB
  const int tid = threadIdx.x; const int c = blockIdx.x; const int n0 = c*CHUNK;
  for (int i = tid; i < CHUNK*16; i += 384){
    sB[i>>4][i&15] = Bc[(size_t)n0*16 + i];
    sC[i>>4][i&15] = Cc[(size_t)n0*16 + i];
  }
  float Ac[16];
  #pragma unroll
  for (int s=0;s<16;s+=4){
    float4 av = *(const float4*)(Alog + tid*16 + s);
    Ac[s]=-__expf(av.x); Ac[s+1]=-__expf(av.y); Ac[s+2]=-__expf(av.z); Ac[s+3]=-__expf(av.w);
  }
  float h[16];
  size_t base = (size_t)c*6144 + (size_t)tid*16;
  #pragma unroll
  for (int s=0;s<16;s+=4){
    float4 hv = *(const float4*)&hi[base+s];
    h[s]=hv.x; h[s+1]=hv.y; h[s+2]=hv.z; h[s+3]=hv.w;
  }
  const float Dpd = Dp[tid];
  const int wid = tid>>6, lane = tid&63;
  __syncthreads();

  for (int half=0; half<2; half++){
    #pragma unroll 4
    for (int nn=0; nn<16; nn++){
      const int t = half*16 + nn;
      size_t n = n0 + t;
      float dl = delta[n*384 + tid];
      float uu = u[n*384 + tid];
      float du = dl * uu;
      float acc = uu * Dpd;
      float4 b0 = *(const float4*)&sB[t][0];
      float4 b1 = *(const float4*)&sB[t][4];
      float4 b2 = *(const float4*)&sB[t][8];
      float4 b3 = *(const float4*)&sB[t][12];
      float4 c0 = *(const float4*)&sC[t][0];
      float4 c1 = *(const float4*)&sC[t][4];
      float4 c2 = *(const float4*)&sC[t][8];
      float4 c3 = *(const float4*)&sC[t][12];
      float Bv[16] = {b0.x,b0.y,b0.z,b0.w, b1.x,b1.y,b1.z,b1.w,
                      b2.x,b2.y,b2.z,b2.w, b3.x,b3.y,b3.z,b3.w};
      float Cv[16] = {c0.x,c0.y,c0.z,c0.w, c1.x,c1.y,c1.z,c1.w,
                      c2.x,c2.y,c2.z,c2.w, c3.x,c3.y,c3.z,c3.w};
      #pragma unroll
      for (int s=0;s<16;s++){
        float a = __expf(dl * Ac[s]);
        h[s] = fmaf(a, h[s], du * Bv[s]);
        acc = fmaf(h[s], Cv[s], acc);
      }
      sY[nn][tid] = acc;
    }
    __syncthreads();
    for (int tt = wid; tt < 16; tt += 6){
      const int t = half*16 + tt;
      float v[6]; float s1=0.f, s2=0.f;
      #pragma unroll
      for (int j=0;j<6;j++){
        v[j] = sY[tt][lane + j*64];
        s1 += v[j]; s2 += v[j]*v[j];
      }
      #pragma unroll
      for (int off=32; off; off>>=1){ s1 += __shfl_xor(s1, off); s2 += __shfl_xor(s2, off); }
      float m = s1*(1.f/384.f);
      float rs = rsqrtf(s2*(1.f/384.f) - m*m + 1e-5f);
      #pragma unroll
      for (int j=0;j<6;j++){
        int cc = lane + j*64;
        float ly = (v[j]-m)*rs*lnw[cc] + lnb[cc];
        float zv = z[(size_t)(n0+t)*384 + cc];
        g_bf[(size_t)(n0+t)*384 + cc] = f2bf(ly * zv * sigmoidf_(zv));
      }
    }
    __syncthreads();
  }
}

// ---------------- Kernel 8 (MFMA): out = g @ W_out + x ----------------
__global__ __launch_bounds__(256) void k8_gemm2(
    const u16* __restrict__ g_bf, const u16* __restrict__ woutf,
    const float* __restrict__ x, float* __restrict__ out)
{
  __shared__ u16 sG[32][392];       // 24.5 KB, stride 784 B -> 2-way alias only
  const int tid = threadIdx.x;
  const int tok0 = blockIdx.x*32;
  for (int i = tid; i < 32*48; i += 256){
    int t = i/48, c8 = i%48;
    *(u16x8*)&sG[t][c8*8] = *(const u16x8*)(g_bf + (size_t)(tok0+t)*384 + c8*8);
  }
  __syncthreads();
  const int wid = tid>>6, lane = tid&63;
  const int wm = wid>>1, wn = wid&1;
  bf16x8 a[12];
  #pragma unroll
  for (int kt=0;kt<12;kt++)
    a[kt] = *(const bf16x8*)&sG[wm*16 + (lane&15)][kt*32 + ((lane>>4)<<3)];
  const bf16x8* wf = (const bf16x8*)woutf;
  const int r0 = tok0 + wm*16 + ((lane>>4)<<2);
  #pragma unroll
  for (int j=0;j<6;j++){
    int nt = wn*6 + j;
    f32x4 acc = (f32x4){0.f,0.f,0.f,0.f};
    const bf16x8* bp = wf + (size_t)nt*12*64 + lane;
    #pragma unroll
    for (int kt=0;kt<12;kt++)
      acc = __builtin_amdgcn_mfma_f32_16x16x32_bf16(a[kt], bp[kt*64], acc, 0,0,0);
    int col = nt*16 + (lane&15);
    #pragma unroll
    for (int r=0;r<4;r++){
      size_t o = (size_t)(r0+r)*192 + col;
      out[o] = acc[r] + x[o];
    }
  }
}

extern "C" void kernel_launch(void* const* d_in, const int* in_sizes, int n_in,
                              void* d_out, int out_size, void* d_ws, size_t ws_size,
                              hipStream_t stream) {
  const float* x      = (const float*)d_in[0];
  const float* ln_in_w= (const float*)d_in[1];
  const float* ln_in_b= (const float*)d_in[2];
  const float* W_in   = (const float*)d_in[3];
  const float* conv_w = (const float*)d_in[4];
  const float* conv_b = (const float*)d_in[5];
  const float* xpw    = (const float*)d_in[6];
  const float* dt_w   = (const float*)d_in[7];
  const float* dt_b   = (const float*)d_in[8];
  const float* A_log  = (const float*)d_in[9];
  const float* Dp     = (const float*)d_in[10];
  const float* ln_o_w = (const float*)d_in[11];
  const float* ln_o_b = (const float*)d_in[12];
  const float* W_out  = (const float*)d_in[13];
  float* out = (float*)d_out;

  float* ws = (float*)d_ws;
  const size_t NDI = (size_t)N_TOK * DI;       // 5,308,416
  u16*  xs_bf = (u16*)ws;           // N x 384 bf16
  float* z    = ws + NDI;           // N x 384
  float* u    = z  + NDI;           // N x 384
  float* dl   = u  + NDI;           // N x 384
  float* Bc   = dl + NDI;           // N x 16
  float* Cc   = Bc + (size_t)N_TOK*DS;
  float* P    = Cc + (size_t)N_TOK*DS;          // NCHUNK x 6144
  float* he   = P  + (size_t)NCHUNK*DI*DS;
  float* hi   = he + (size_t)NCHUNK*DI*DS;
  u16*  winf  = (u16*)P;                         // alias P: dead before k234 writes P
  u16*  woutf = (u16*)(hi + (size_t)NCHUNK*DI*DS);
  u16*  xpwf  = woutf + (size_t)144*512;
  u16*  g_bf  = (u16*)P;                         // alias P: dead after k5; k67 only reads hi

  k0_prep            <<<117, 256, 0, stream>>>(W_in, W_out, xpw, winf, woutf, xpwf);
  k1_ln_gemm1        <<<N_TOK/32, 256, 0, stream>>>(x, ln_in_w, ln_in_b, winf, xs_bf, z);
  k234_conv_xproj_scan1<<<NCHUNK, 384, 0, stream>>>(xs_bf, conv_w, conv_b, xpwf,
                                                    dt_w, dt_b, A_log, u, dl, Bc, Cc, P, he);
  k5_scan2           <<<24, 256, 0, stream>>>(P, he, hi);
  k67_scan3_lngate   <<<NCHUNK, 384, 0, stream>>>(dl, u, Bc, Cc, A_log, Dp, hi, z,
                                                  ln_o_w, ln_o_b, g_bf);
  k8_gemm2           <<<N_TOK/32, 256, 0, stream>>>(g_bf, woutf, x, out);
}

// Round 9
// 181.756 us; speedup vs baseline: 1.0489x; 1.0489x over previous
//
#include <hip/hip_runtime.h>
#include <math.h>

#define N_TOK 13824
#define DM 192
#define DI 384
#define DS 16
#define DTR 12
#define CHUNK 32
#define NCHUNK 432   // 13824 / 32

typedef unsigned short u16;
typedef __attribute__((ext_vector_type(8))) short bf16x8;
typedef __attribute__((ext_vector_type(8))) unsigned short u16x8;
typedef __attribute__((ext_vector_type(4))) float f32x4;

__device__ __forceinline__ float sigmoidf_(float x){ return 1.f/(1.f+__expf(-x)); }
__device__ __forceinline__ u16 f2bf(float f){
  union { float f; unsigned u; } c; c.f = f;
  unsigned u = c.u;
  u += 0x7fffu + ((u>>16)&1u);
  return (u16)(u>>16);
}
__device__ __forceinline__ float bf2f(u16 v){
  union { unsigned u; float f; } c; c.u = ((unsigned)v)<<16; return c.f;
}

// ---------------- Kernel 0: convert W_in / W_out / xpw to bf16 MFMA B-fragment order ----
__global__ __launch_bounds__(256) void k0_prep(
    const float* __restrict__ Win, const float* __restrict__ Wout,
    const float* __restrict__ xpw,
    u16* __restrict__ winf, u16* __restrict__ woutf, u16* __restrict__ xpwf)
{
  const int b = blockIdx.x, tid = threadIdx.x;
  if (b < 72) {                       // W_in: 48 nt x 6 kt = 288 frags
    int g = b*256 + tid; int fi = g>>6, lane = g&63;
    int nt = fi/6, kt = fi%6;
    int n = nt*16 + (lane&15);
    int kb = kt*32 + ((lane>>4)<<3);
    u16 v[8];
    #pragma unroll
    for (int i=0;i<8;i++) v[i] = f2bf(Win[(size_t)(kb+i)*768 + n]);
    u16* dst = winf + ((size_t)fi*64 + lane)*8;
    #pragma unroll
    for (int i=0;i<8;i++) dst[i] = v[i];
  } else if (b < 108) {               // W_out: 12 nt x 12 kt = 144 frags
    int g = (b-72)*256 + tid; int fi = g>>6, lane = g&63;
    int nt = fi/12, kt = fi%12;
    int n = nt*16 + (lane&15);
    int kb = kt*32 + ((lane>>4)<<3);
    u16 v[8];
    #pragma unroll
    for (int i=0;i<8;i++) v[i] = f2bf(Wout[(size_t)(kb+i)*192 + n]);
    u16* dst = woutf + ((size_t)fi*64 + lane)*8;
    #pragma unroll
    for (int i=0;i<8;i++) dst[i] = v[i];
  } else {                            // xpw: 3 nt x 12 kt = 36 frags (cols 44..47 zero)
    int g = (b-108)*256 + tid; int fi = g>>6, lane = g&63;
    if (fi < 36) {
      int nt = fi/12, kt = fi%12;
      int n = nt*16 + (lane&15);
      int kb = kt*32 + ((lane>>4)<<3);
      u16 v[8];
      #pragma unroll
      for (int i=0;i<8;i++) v[i] = (n < 44) ? f2bf(xpw[(size_t)(kb+i)*44 + n]) : (u16)0;
      u16* dst = xpwf + ((size_t)fi*64 + lane)*8;
      #pragma unroll
      for (int i=0;i<8;i++) dst[i] = v[i];
    }
  }
}

// ---------------- Kernel 1 (MFMA): LayerNorm(x) @ W_in -> xs (bf16), z (fp32) ----------------
__global__ __launch_bounds__(256) void k1_ln_gemm1(
    const float* __restrict__ x, const float* __restrict__ lnw,
    const float* __restrict__ lnb, const u16* __restrict__ winf,
    u16* __restrict__ xs_bf, float* __restrict__ z)
{
  __shared__ u16 sA[32][200];        // 12.5 KB
  const int tid = threadIdx.x;
  const int tok0 = blockIdx.x * 32;
  const int wid = tid>>6, lane = tid&63;

  {
    int t = wid*8 + (lane>>3);
    int l8 = lane&7;
    const float* xrow = x + (size_t)(tok0+t)*192 + l8*4;
    float4 v[6]; float s=0.f, s2=0.f;
    #pragma unroll
    for (int j=0;j<6;j++){
      v[j] = *(const float4*)(xrow + j*32);
      s  += v[j].x+v[j].y+v[j].z+v[j].w;
      s2 += v[j].x*v[j].x + v[j].y*v[j].y + v[j].z*v[j].z + v[j].w*v[j].w;
    }
    #pragma unroll
    for (int off=4; off; off>>=1){ s += __shfl_xor(s, off, 8); s2 += __shfl_xor(s2, off, 8); }
    float m = s*(1.f/192.f);
    float rs = rsqrtf(s2*(1.f/192.f) - m*m + 1e-5f);
    #pragma unroll
    for (int j=0;j<6;j++){
      int k = j*32 + l8*4;
      float4 lw = *(const float4*)(lnw+k);
      float4 lb = *(const float4*)(lnb+k);
      sA[t][k+0] = f2bf((v[j].x-m)*rs*lw.x+lb.x);
      sA[t][k+1] = f2bf((v[j].y-m)*rs*lw.y+lb.y);
      sA[t][k+2] = f2bf((v[j].z-m)*rs*lw.z+lb.z);
      sA[t][k+3] = f2bf((v[j].w-m)*rs*lw.w+lb.w);
    }
  }
  __syncthreads();

  const int wm = wid>>1, wn = wid&1;
  bf16x8 a[6];
  #pragma unroll
  for (int kt=0;kt<6;kt++)
    a[kt] = *(const bf16x8*)&sA[wm*16 + (lane&15)][kt*32 + ((lane>>4)<<3)];

  const bf16x8* wf = (const bf16x8*)winf;
  f32x4 acc[24];
  #pragma unroll
  for (int j=0;j<24;j++) acc[j] = (f32x4){0.f,0.f,0.f,0.f};

  #pragma unroll
  for (int j=0;j<24;j++){
    int nt = wn*24 + j;
    const bf16x8* bp = wf + (size_t)nt*6*64 + lane;
    #pragma unroll
    for (int kt=0;kt<6;kt++)
      acc[j] = __builtin_amdgcn_mfma_f32_16x16x32_bf16(a[kt], bp[kt*64], acc[j], 0,0,0);
  }

  const int r0 = tok0 + wm*16 + ((lane>>4)<<2);
  if (wn == 0){
    #pragma unroll
    for (int j=0;j<24;j++){
      int cc = j*16 + (lane&15);
      #pragma unroll
      for (int r=0;r<4;r++)
        xs_bf[(size_t)(r0+r)*384 + cc] = f2bf(acc[j][r]);
    }
  } else {
    #pragma unroll
    for (int j=0;j<24;j++){
      int cc = j*16 + (lane&15);
      #pragma unroll
      for (int r=0;r<4;r++)
        z[(size_t)(r0+r)*384 + cc] = acc[j][r];
    }
  }
}

// ---------------- Kernel 234 (fused, 12 waves): conv3+SiLU + x_proj MFMA + dt_proj + scan1 ----
// One block per chunk, 768 threads. conv: thread=(channel, token-half).
// scan: thread=(channel, state-half) -> h[8]/thread, dt-dot duplicated.
__global__ __launch_bounds__(768) void k234_conv_xproj_scan1(
    const u16* __restrict__ xs_bf, const float* __restrict__ cw, const float* __restrict__ cb,
    const u16* __restrict__ xpwf, const float* __restrict__ dtw, const float* __restrict__ dtb,
    const float* __restrict__ Alog,
    float* __restrict__ u_out, float* __restrict__ delta,
    float* __restrict__ Bc, float* __restrict__ Cc,
    float* __restrict__ P, float* __restrict__ he)
{
  __shared__ u16 sU16[32][392];    // 25.1 KB
  __shared__ float sdbl[32][48];   //  6 KB
  const int tid = threadIdx.x;
  const int c = blockIdx.x; const int n0 = c*CHUNK;
  const int hf = (tid >= 384) ? 1 : 0;
  const int ch = tid - hf*384;

  // conv + silu: each half-group does 16 tokens of its channel column
  {
    const float w0 = cw[ch*3+0], w1 = cw[ch*3+1], w2 = cw[ch*3+2], bb = cb[ch];
    const u16* xp = xs_bf + ch;
    const int b0 = n0 + hf*16;
    float vm = (b0 > 0) ? bf2f(xp[(size_t)(b0-1)*384]) : 0.f;
    float vc = bf2f(xp[(size_t)b0*384]);
    #pragma unroll 4
    for (int t=0;t<16;t++){
      int np1 = b0 + t + 1;
      float vp = (np1 < N_TOK) ? bf2f(xp[(size_t)np1*384]) : 0.f;
      float v = fmaf(w0,vm, fmaf(w1,vc, fmaf(w2,vp, bb)));
      float uv = v * sigmoidf_(v);
      u_out[(size_t)(b0+t)*384 + ch] = uv;
      sU16[hf*16 + t][ch] = f2bf(uv);
      vm = vc; vc = vp;
    }
  }
  __syncthreads();

  // x_proj MFMA on waves 0-5 (2 M-halves x 3 n-tiles, 12 k-tiles)
  const int wid = tid>>6, lane = tid&63;
  if (wid < 6) {
    const int wm = wid & 1, wnt = wid >> 1;
    const int arow = wm*16 + (lane&15);
    f32x4 acc = (f32x4){0.f,0.f,0.f,0.f};
    const bf16x8* bp = (const bf16x8*)xpwf + (size_t)wnt*12*64 + lane;
    #pragma unroll
    for (int kt=0;kt<12;kt++){
      bf16x8 a = *(const bf16x8*)&sU16[arow][kt*32 + ((lane>>4)<<3)];
      acc = __builtin_amdgcn_mfma_f32_16x16x32_bf16(a, bp[kt*64], acc, 0,0,0);
    }
    int ccol = wnt*16 + (lane&15);
    int r0 = wm*16 + ((lane>>4)<<2);
    #pragma unroll
    for (int r=0;r<4;r++) sdbl[r0+r][ccol] = acc[r];
  }
  __syncthreads();

  for (int i=tid;i<32*16;i+=768){
    int t=i>>4, s=i&15;
    Bc[(size_t)(n0+t)*16+s] = sdbl[t][12+s];
    Cc[(size_t)(n0+t)*16+s] = sdbl[t][28+s];
  }

  // scan phase 1: thread = (channel, state-half of 8)
  float Ac[8];
  #pragma unroll
  for (int s=0;s<8;s+=4){
    float4 av = *(const float4*)(Alog + ch*16 + hf*8 + s);
    Ac[s]=-__expf(av.x); Ac[s+1]=-__expf(av.y); Ac[s+2]=-__expf(av.z); Ac[s+3]=-__expf(av.w);
  }
  float wr[12];
  #pragma unroll
  for (int r=0;r<12;r++) wr[r] = dtw[r*384 + ch];
  const float db_ = dtb[ch];
  float h[8];
  #pragma unroll
  for (int s=0;s<8;s++) h[s]=0.f;
  float dlsum = 0.f;

  #pragma unroll 4
  for (int t=0;t<32;t++){
    float4 d0 = *(const float4*)&sdbl[t][0];
    float4 d1 = *(const float4*)&sdbl[t][4];
    float4 d2 = *(const float4*)&sdbl[t][8];
    float a0 = db_;
    a0=fmaf(d0.x,wr[0],a0); a0=fmaf(d0.y,wr[1],a0); a0=fmaf(d0.z,wr[2],a0); a0=fmaf(d0.w,wr[3],a0);
    a0=fmaf(d1.x,wr[4],a0); a0=fmaf(d1.y,wr[5],a0); a0=fmaf(d1.z,wr[6],a0); a0=fmaf(d1.w,wr[7],a0);
    a0=fmaf(d2.x,wr[8],a0); a0=fmaf(d2.y,wr[9],a0); a0=fmaf(d2.z,wr[10],a0); a0=fmaf(d2.w,wr[11],a0);
    float dl = fmaxf(a0,0.f) + log1pf(__expf(-fabsf(a0)));
    if (hf == 0) delta[(size_t)(n0+t)*384 + ch] = dl;
    dlsum += dl;
    float du = dl * bf2f(sU16[t][ch]);
    float4 bv0 = *(const float4*)&sdbl[t][12 + hf*8];
    float4 bv1 = *(const float4*)&sdbl[t][16 + hf*8];
    float Bv[8] = {bv0.x,bv0.y,bv0.z,bv0.w, bv1.x,bv1.y,bv1.z,bv1.w};
    #pragma unroll
    for (int s=0;s<8;s++){
      float a = __expf(dl * Ac[s]);
      h[s] = fmaf(a, h[s], du * Bv[s]);
    }
  }
  size_t base = (size_t)c*6144 + (size_t)ch*16 + hf*8;
  #pragma unroll
  for (int s=0;s<8;s+=4){
    *(float4*)&P[base+s]  = make_float4(__expf(dlsum*Ac[s]),   __expf(dlsum*Ac[s+1]),
                                        __expf(dlsum*Ac[s+2]), __expf(dlsum*Ac[s+3]));
    *(float4*)&he[base+s] = make_float4(h[s],h[s+1],h[s+2],h[s+3]);
  }
}

// ---------------- Kernel 5: scan phase 2 (cross-chunk prefix, sw-pipelined) ----------------
__global__ __launch_bounds__(256) void k5_scan2(
    const float* __restrict__ P, const float* __restrict__ he, float* __restrict__ hi)
{
  const int idx = blockIdx.x*256 + threadIdx.x;   // 0..6143
  float H = 0.f;
  float pA[8], eA[8], pB[8], eB[8];
  #pragma unroll
  for (int i = 0; i < 8; i++) {
    size_t o = (size_t)i*6144 + idx; pA[i] = P[o]; eA[i] = he[o];
  }
  for (int c0 = 0; c0 < NCHUNK; c0 += 16) {
    #pragma unroll
    for (int i = 0; i < 8; i++) {
      size_t o = (size_t)(c0+8+i)*6144 + idx; pB[i] = P[o]; eB[i] = he[o];
    }
    #pragma unroll
    for (int i = 0; i < 8; i++) {
      size_t o = (size_t)(c0+i)*6144 + idx; hi[o] = H; H = fmaf(pA[i], H, eA[i]);
    }
    if (c0 + 16 < NCHUNK) {
      #pragma unroll
      for (int i = 0; i < 8; i++) {
        size_t o = (size_t)(c0+16+i)*6144 + idx; pA[i] = P[o]; eA[i] = he[o];
      }
    }
    #pragma unroll
    for (int i = 0; i < 8; i++) {
      size_t o = (size_t)(c0+8+i)*6144 + idx; hi[o] = H; H = fmaf(pB[i], H, eB[i]);
    }
  }
}

// ---------------- Kernel 67 (fused, 12 waves): scan phase 3 + LayerNorm(y)*silu(z) -> g_bf ----
// thread = (channel, state-half); partial PV sums in sYa/sYb, LN sums both.
__global__ __launch_bounds__(768) void k67_scan3_lngate(
    const float* __restrict__ delta, const float* __restrict__ u,
    const float* __restrict__ Bc, const float* __restrict__ Cc,
    const float* __restrict__ Alog, const float* __restrict__ Dp,
    const float* __restrict__ hi, const float* __restrict__ z,
    const float* __restrict__ lnw, const float* __restrict__ lnb,
    u16* __restrict__ g_bf)
{
  __shared__ float sB[CHUNK][16], sC[CHUNK][16];  // 4 KB
  __shared__ float sYa[16][384];                  // 24 KB
  __shared__ float sYb[16][384];                  // 24 KB
  const int tid = threadIdx.x; const int c = blockIdx.x; const int n0 = c*CHUNK;
  const int hf = (tid >= 384) ? 1 : 0;
  const int ch = tid - hf*384;
  for (int i = tid; i < CHUNK*16; i += 768){
    sB[i>>4][i&15] = Bc[(size_t)n0*16 + i];
    sC[i>>4][i&15] = Cc[(size_t)n0*16 + i];
  }
  float Ac[8];
  #pragma unroll
  for (int s=0;s<8;s+=4){
    float4 av = *(const float4*)(Alog + ch*16 + hf*8 + s);
    Ac[s]=-__expf(av.x); Ac[s+1]=-__expf(av.y); Ac[s+2]=-__expf(av.z); Ac[s+3]=-__expf(av.w);
  }
  float h[8];
  size_t base = (size_t)c*6144 + (size_t)ch*16 + hf*8;
  #pragma unroll
  for (int s=0;s<8;s+=4){
    float4 hv = *(const float4*)&hi[base+s];
    h[s]=hv.x; h[s+1]=hv.y; h[s+2]=hv.z; h[s+3]=hv.w;
  }
  const float Dpd = Dp[ch];
  const int wid = tid>>6, lane = tid&63;
  __syncthreads();

  for (int half=0; half<2; half++){
    #pragma unroll 4
    for (int nn=0; nn<16; nn++){
      const int t = half*16 + nn;
      size_t n = n0 + t;
      float dl = delta[n*384 + ch];
      float uu = u[n*384 + ch];
      float du = dl * uu;
      float acc = hf ? 0.f : uu * Dpd;
      float4 bv0 = *(const float4*)&sB[t][hf*8];
      float4 bv1 = *(const float4*)&sB[t][hf*8+4];
      float4 cv0 = *(const float4*)&sC[t][hf*8];
      float4 cv1 = *(const float4*)&sC[t][hf*8+4];
      float Bv[8] = {bv0.x,bv0.y,bv0.z,bv0.w, bv1.x,bv1.y,bv1.z,bv1.w};
      float Cv[8] = {cv0.x,cv0.y,cv0.z,cv0.w, cv1.x,cv1.y,cv1.z,cv1.w};
      #pragma unroll
      for (int s=0;s<8;s++){
        float a = __expf(dl * Ac[s]);
        h[s] = fmaf(a, h[s], du * Bv[s]);
        acc = fmaf(h[s], Cv[s], acc);
      }
      if (hf == 0) sYa[nn][ch] = acc; else sYb[nn][ch] = acc;
    }
    __syncthreads();
    for (int tt = wid; tt < 16; tt += 12){
      const int t = half*16 + tt;
      float v[6]; float s1=0.f, s2=0.f;
      #pragma unroll
      for (int j=0;j<6;j++){
        int cc = lane + j*64;
        v[j] = sYa[tt][cc] + sYb[tt][cc];
        s1 += v[j]; s2 += v[j]*v[j];
      }
      #pragma unroll
      for (int off=32; off; off>>=1){ s1 += __shfl_xor(s1, off); s2 += __shfl_xor(s2, off); }
      float m = s1*(1.f/384.f);
      float rs = rsqrtf(s2*(1.f/384.f) - m*m + 1e-5f);
      #pragma unroll
      for (int j=0;j<6;j++){
        int cc = lane + j*64;
        float ly = (v[j]-m)*rs*lnw[cc] + lnb[cc];
        float zv = z[(size_t)(n0+t)*384 + cc];
        g_bf[(size_t)(n0+t)*384 + cc] = f2bf(ly * zv * sigmoidf_(zv));
      }
    }
    __syncthreads();
  }
}

// ---------------- Kernel 8 (MFMA): out = g @ W_out + x ----------------
__global__ __launch_bounds__(256) void k8_gemm2(
    const u16* __restrict__ g_bf, const u16* __restrict__ woutf,
    const float* __restrict__ x, float* __restrict__ out)
{
  __shared__ u16 sG[32][392];       // 24.5 KB
  const int tid = threadIdx.x;
  const int tok0 = blockIdx.x*32;
  for (int i = tid; i < 32*48; i += 256){
    int t = i/48, c8 = i%48;
    *(u16x8*)&sG[t][c8*8] = *(const u16x8*)(g_bf + (size_t)(tok0+t)*384 + c8*8);
  }
  __syncthreads();
  const int wid = tid>>6, lane = tid&63;
  const int wm = wid>>1, wn = wid&1;
  bf16x8 a[12];
  #pragma unroll
  for (int kt=0;kt<12;kt++)
    a[kt] = *(const bf16x8*)&sG[wm*16 + (lane&15)][kt*32 + ((lane>>4)<<3)];
  const bf16x8* wf = (const bf16x8*)woutf;
  const int r0 = tok0 + wm*16 + ((lane>>4)<<2);
  #pragma unroll
  for (int j=0;j<6;j++){
    int nt = wn*6 + j;
    f32x4 acc = (f32x4){0.f,0.f,0.f,0.f};
    const bf16x8* bp = wf + (size_t)nt*12*64 + lane;
    #pragma unroll
    for (int kt=0;kt<12;kt++)
      acc = __builtin_amdgcn_mfma_f32_16x16x32_bf16(a[kt], bp[kt*64], acc, 0,0,0);
    int col = nt*16 + (lane&15);
    #pragma unroll
    for (int r=0;r<4;r++){
      size_t o = (size_t)(r0+r)*192 + col;
      out[o] = acc[r] + x[o];
    }
  }
}

extern "C" void kernel_launch(void* const* d_in, const int* in_sizes, int n_in,
                              void* d_out, int out_size, void* d_ws, size_t ws_size,
                              hipStream_t stream) {
  const float* x      = (const float*)d_in[0];
  const float* ln_in_w= (const float*)d_in[1];
  const float* ln_in_b= (const float*)d_in[2];
  const float* W_in   = (const float*)d_in[3];
  const float* conv_w = (const float*)d_in[4];
  const float* conv_b = (const float*)d_in[5];
  const float* xpw    = (const float*)d_in[6];
  const float* dt_w   = (const float*)d_in[7];
  const float* dt_b   = (const float*)d_in[8];
  const float* A_log  = (const float*)d_in[9];
  const float* Dp     = (const float*)d_in[10];
  const float* ln_o_w = (const float*)d_in[11];
  const float* ln_o_b = (const float*)d_in[12];
  const float* W_out  = (const float*)d_in[13];
  float* out = (float*)d_out;

  float* ws = (float*)d_ws;
  const size_t NDI = (size_t)N_TOK * DI;       // 5,308,416
  u16*  xs_bf = (u16*)ws;           // N x 384 bf16
  float* z    = ws + NDI;           // N x 384
  float* u    = z  + NDI;           // N x 384
  float* dl   = u  + NDI;           // N x 384
  float* Bc   = dl + NDI;           // N x 16
  float* Cc   = Bc + (size_t)N_TOK*DS;
  float* P    = Cc + (size_t)N_TOK*DS;          // NCHUNK x 6144
  float* he   = P  + (size_t)NCHUNK*DI*DS;
  float* hi   = he + (size_t)NCHUNK*DI*DS;
  u16*  winf  = (u16*)P;                         // alias P: dead before k234 writes P
  u16*  woutf = (u16*)(hi + (size_t)NCHUNK*DI*DS);
  u16*  xpwf  = woutf + (size_t)144*512;
  u16*  g_bf  = (u16*)P;                         // alias P: dead after k5; k67 only reads hi

  k0_prep            <<<117, 256, 0, stream>>>(W_in, W_out, xpw, winf, woutf, xpwf);
  k1_ln_gemm1        <<<N_TOK/32, 256, 0, stream>>>(x, ln_in_w, ln_in_b, winf, xs_bf, z);
  k234_conv_xproj_scan1<<<NCHUNK, 768, 0, stream>>>(xs_bf, conv_w, conv_b, xpwf,
                                                    dt_w, dt_b, A_log, u, dl, Bc, Cc, P, he);
  k5_scan2           <<<24, 256, 0, stream>>>(P, he, hi);
  k67_scan3_lngate   <<<NCHUNK, 768, 0, stream>>>(dl, u, Bc, Cc, A_log, Dp, hi, z,
                                                  ln_o_w, ln_o_b, g_bf);
  k8_gemm2           <<<N_TOK/32, 256, 0, stream>>>(g_bf, woutf, x, out);
}